// Round 1
// baseline (268.547 us; speedup 1.0000x reference)
//
#include <hip/hip_runtime.h>
#include <math.h>

// Problem constants
#define BB    64        // batch
#define NEC   40000     // num entities
#define NRC   500       // num relations
#define D1C   200
#define D2C   200
#define LLC   64        // literals
#define BN_EPS 1e-5f
#define LOG2E 1.4426950408889634f

// ws layout (floats):
//   xT   [D1][64]   @ 0       (bn0 output, transposed: xT[i*64+b])
//   rT   [D2][64]   @ 12800   (gathered relation rows, rT[k*64+b])
//   aT   [L ][64]   @ 25600   ((n_h - c)*s, transposed)
//   wT   [L ][64]   @ 29696   (gathered nf rows, transposed)
//   sl   [L ]       @ 33792   (s[l] = sqrt(log2e/var_l[l]))
//   x2T  [D1][64]   @ 33856   (bn1 output, transposed)
//   y    [D2*D1][64]@ 46656   (per-k partials, r folded in)  2,560,000 floats
#define WS_XT   0
#define WS_RT   12800
#define WS_AT   25600
#define WS_WT   29696
#define WS_SL   33792
#define WS_X2T  33856
#define WS_Y    46656

// ---------------------------------------------------------------------------
// Kernel A: gathers + bn0 + literal pre-transforms. Tiny; 3 blocks.
// ---------------------------------------------------------------------------
__global__ __launch_bounds__(256) void prep_kernel(
    const int* __restrict__ e1_idx, const int* __restrict__ r_idx,
    const float* __restrict__ E, const float* __restrict__ R,
    const float* __restrict__ lits, const float* __restrict__ c,
    const float* __restrict__ var_l, const float* __restrict__ nf,
    const float* __restrict__ bn0g, const float* __restrict__ bn0b,
    float* __restrict__ ws) {
  float* xT = ws + WS_XT;
  float* rT = ws + WS_RT;
  float* aT = ws + WS_AT;
  float* wT = ws + WS_WT;
  float* sl = ws + WS_SL;
  int tid = threadIdx.x;

  if (blockIdx.x == 0) {
    // bn0 over batch axis: thread = feature j
    if (tid < D1C) {
      int j = tid;
      float sum = 0.f, sq = 0.f;
      for (int b = 0; b < BB; b++) {
        float e = E[e1_idx[b] * D1C + j];
        sum += e; sq += e * e;
      }
      float mean = sum * (1.f / 64.f);
      float var  = sq  * (1.f / 64.f) - mean * mean;
      float inv  = __builtin_amdgcn_rsqf(var + BN_EPS);
      float g    = bn0g[j] * inv;
      float be   = bn0b[j] - mean * g;
      for (int b = 0; b < BB; b++) {
        xT[j * 64 + b] = g * E[e1_idx[b] * D1C + j] + be;
      }
    }
  } else if (blockIdx.x == 1) {
    // gather R rows (transposed)
    for (int idx = tid; idx < D2C * 64; idx += 256) {
      int k = idx >> 6, b = idx & 63;
      rT[idx] = R[r_idx[b] * D2C + k];
    }
  } else {
    // literal branch precompute: aT[l][b] = (n_h - c)*s ; wT[l][b] = nf[r]
    for (int idx = tid; idx < LLC * 64; idx += 256) {
      int l = idx >> 6, b = idx & 63;
      float s = sqrtf(LOG2E / var_l[l]);
      aT[idx] = (lits[e1_idx[b] * LLC + l] - c[l]) * s;
      wT[idx] = nf[r_idx[b] * LLC + l];
    }
    if (tid < LLC) sl[tid] = sqrtf(LOG2E / var_l[tid]);
  }
}

// ---------------------------------------------------------------------------
// Stage 1: y[k][j][b] = r[b,k] * sum_i x[b,i] * W[k,i,j]
// lane = b (64 exactly). W row values are wave-uniform -> scalar loads.
// grid (k=200, jq=5), block 128 (2 waves x 20-j tiles).
// ---------------------------------------------------------------------------
__global__ __launch_bounds__(128) void stage1_kernel(
    const float* __restrict__ W, const float* __restrict__ ws_in,
    float* __restrict__ y) {
  const float* xT = ws_in + WS_XT;
  const float* rT = ws_in + WS_RT;
  int k = blockIdx.x, jq = blockIdx.y;
  int lane = threadIdx.x & 63;
  int wid = __builtin_amdgcn_readfirstlane(threadIdx.x >> 6);
  int j0 = jq * 40 + wid * 20;

  float r = rT[k * 64 + lane];
  float acc[20];
#pragma unroll
  for (int jj = 0; jj < 20; jj++) acc[jj] = 0.f;

  const float* Wk = W + (k * D1C) * D1C + j0;   // W[k][i][j0..]
  for (int i = 0; i < D1C; i++) {
    float xv = xT[i * 64 + lane];               // coalesced vector load
    const float* wr = Wk + i * D1C;             // wave-uniform -> s_load
#pragma unroll
    for (int jj = 0; jj < 20; jj++) acc[jj] += xv * wr[jj];
  }

  float* yo = y + (k * D1C + j0) * 64 + lane;
#pragma unroll
  for (int jj = 0; jj < 20; jj++) yo[jj * 64] = r * acc[jj];
}

// ---------------------------------------------------------------------------
// Kernel C: x_out[b,j] = sum_k y[k][j][b], then bn1 over b -> x2T[j][b]
// block = j (200 blocks), 256 threads: lane=b, 4 k-quarters.
// ---------------------------------------------------------------------------
__global__ __launch_bounds__(256) void reduce_bn1_kernel(
    const float* __restrict__ y, const float* __restrict__ bn1g,
    const float* __restrict__ bn1b, float* __restrict__ ws) {
  float* x2T = ws + WS_X2T;
  int j = blockIdx.x;
  int tid = threadIdx.x, b = tid & 63, kq = tid >> 6;

  float s = 0.f;
  const float* yp = y + (kq * 50 * D1C + j) * 64 + b;
  for (int k = 0; k < 50; k++) s += yp[k * D1C * 64];

  __shared__ float part[256];
  part[tid] = s;
  __syncthreads();
  if (tid < 64) {
    float v = part[tid] + part[64 + tid] + part[128 + tid] + part[192 + tid];
    float sum = v, sq = v * v;
#pragma unroll
    for (int o = 32; o > 0; o >>= 1) {
      sum += __shfl_xor(sum, o, 64);
      sq  += __shfl_xor(sq,  o, 64);
    }
    float mean = sum * (1.f / 64.f);
    float var  = sq  * (1.f / 64.f) - mean * mean;
    float inv  = __builtin_amdgcn_rsqf(var + BN_EPS);
    float g    = bn1g[j] * inv;
    float be   = bn1b[j] - mean * g;
    x2T[j * 64 + tid] = g * v + be;
  }
}

// ---------------------------------------------------------------------------
// Final: out[b,n] = sigmoid( sum_j x2[b,j]E[n,j] + sum_l w[b,l]*exp2(-t^2) )
// lane = n-offset (64 n per block), 2 waves x 32-b tiles, grid 625.
// E tile transposed through LDS (2 halves, pad 101); lits tile scaled+
// transposed (pad 65). x2/a/w reads are wave-uniform -> s_load.
// ---------------------------------------------------------------------------
__global__ __launch_bounds__(128) void final_kernel(
    const float* __restrict__ E, const float* __restrict__ lits,
    const float* __restrict__ ws, float* __restrict__ out) {
  const float* aT  = ws + WS_AT;
  const float* wT  = ws + WS_WT;
  const float* sl  = ws + WS_SL;
  const float* x2T = ws + WS_X2T;

  __shared__ float Es[64 * 101];
  __shared__ float Ls[64 * 65];

  int n0 = blockIdx.x * 64;
  int tid = threadIdx.x;
  int lane = tid & 63;
  int woff = __builtin_amdgcn_readfirstlane(tid >> 6) * 32;

  // stage scaled literals, transposed: Ls[l][row]
  for (int idx = tid; idx < 64 * 16; idx += 128) {
    int row = idx >> 4, c4 = idx & 15;
    const float4 v = *(const float4*)(lits + (n0 + row) * LLC + c4 * 4);
    int l = c4 * 4;
    Ls[(l + 0) * 65 + row] = v.x * sl[l + 0];
    Ls[(l + 1) * 65 + row] = v.y * sl[l + 1];
    Ls[(l + 2) * 65 + row] = v.z * sl[l + 2];
    Ls[(l + 3) * 65 + row] = v.w * sl[l + 3];
  }

  float acc[32];
#pragma unroll
  for (int bb = 0; bb < 32; bb++) acc[bb] = 0.f;

  // score_l in two j-halves (keeps LDS under 64 KB)
  for (int h = 0; h < 2; h++) {
    __syncthreads();
    for (int idx = tid; idx < 64 * 25; idx += 128) {
      int row = idx / 25, c4 = idx % 25;
      const float4 v = *(const float4*)(E + (n0 + row) * D1C + h * 100 + c4 * 4);
      Es[row * 101 + c4 * 4 + 0] = v.x;
      Es[row * 101 + c4 * 4 + 1] = v.y;
      Es[row * 101 + c4 * 4 + 2] = v.z;
      Es[row * 101 + c4 * 4 + 3] = v.w;
    }
    __syncthreads();
    const float* x2p = x2T + h * 100 * 64 + woff;
    for (int j = 0; j < 100; j++) {
      float ev = Es[lane * 101 + j];          // conflict-free (stride 101)
      const float* xw = x2p + j * 64;         // wave-uniform -> s_load
#pragma unroll
      for (int bb = 0; bb < 32; bb++) acc[bb] += ev * xw[bb];
    }
  }

  // score_n: KBLN gaussian-kernel branch
  for (int l = 0; l < LLC; l++) {
    float lit = Ls[l * 65 + lane];
    const float* aw = aT + l * 64 + woff;     // wave-uniform -> s_load
    const float* ww = wT + l * 64 + woff;
#pragma unroll
    for (int bb = 0; bb < 32; bb++) {
      float t = aw[bb] - lit;
      acc[bb] += ww[bb] * __builtin_amdgcn_exp2f(-t * t);
    }
  }

  // sigmoid + coalesced store
#pragma unroll
  for (int bb = 0; bb < 32; bb++) {
    float s = acc[bb];
    float e = __builtin_amdgcn_exp2f(-LOG2E * s);
    out[(woff + bb) * NEC + n0 + lane] = __builtin_amdgcn_rcpf(1.f + e);
  }
}

// ---------------------------------------------------------------------------
extern "C" void kernel_launch(void* const* d_in, const int* in_sizes, int n_in,
                              void* d_out, int out_size, void* d_ws, size_t ws_size,
                              hipStream_t stream) {
  (void)in_sizes; (void)n_in; (void)out_size; (void)ws_size;
  const int*   e1    = (const int*)d_in[0];
  const int*   ri    = (const int*)d_in[1];
  const float* E     = (const float*)d_in[2];
  const float* R     = (const float*)d_in[3];
  const float* W     = (const float*)d_in[4];
  const float* lits  = (const float*)d_in[5];
  const float* c     = (const float*)d_in[6];
  const float* var_l = (const float*)d_in[7];
  const float* nf    = (const float*)d_in[8];
  const float* bn0g  = (const float*)d_in[9];
  const float* bn0b  = (const float*)d_in[10];
  const float* bn1g  = (const float*)d_in[11];
  const float* bn1b  = (const float*)d_in[12];
  float* out = (float*)d_out;
  float* ws  = (float*)d_ws;
  float* y   = ws + WS_Y;

  prep_kernel<<<3, 256, 0, stream>>>(e1, ri, E, R, lits, c, var_l, nf,
                                     bn0g, bn0b, ws);
  stage1_kernel<<<dim3(200, 5), 128, 0, stream>>>(W, ws, y);
  reduce_bn1_kernel<<<200, 256, 0, stream>>>(y, bn1g, bn1b, ws);
  final_kernel<<<625, 128, 0, stream>>>(E, lits, ws, out);
}

// Round 2
// 226.517 us; speedup vs baseline: 1.1855x; 1.1855x over previous
//
#include <hip/hip_runtime.h>
#include <math.h>

// Problem constants
#define BB    64        // batch
#define NEC   40000     // num entities
#define NRC   500       // num relations
#define D1C   200
#define D2C   200
#define LLC   64        // literals
#define BN_EPS 1e-5f
#define LOG2E 1.4426950408889634f

// ws layout (floats):
//   xT   [D1][64]   @ 0       (bn0 output, transposed: xT[i*64+b])
//   rT   [D2][64]   @ 12800   (gathered relation rows, rT[k*64+b])
//   aT   [L ][64]   @ 25600   ((n_h - c)*s, transposed)
//   wT   [L ][64]   @ 29696   (gathered nf rows, transposed)
//   sl   [L ]       @ 33792   (s[l] = sqrt(log2e/var_l[l]))
//   x2T  [D1][64]   @ 33856   (bn1 output, transposed)
//   y    [k][j][64] @ 46656   (per-k partials, r folded in)  2,560,000 floats
#define WS_XT   0
#define WS_RT   12800
#define WS_AT   25600
#define WS_WT   29696
#define WS_SL   33792
#define WS_X2T  33856
#define WS_Y    46656

// ---------------------------------------------------------------------------
// Kernel A: gathers + bn0 + literal pre-transforms. Tiny; 3 blocks.
// ---------------------------------------------------------------------------
__global__ __launch_bounds__(256) void prep_kernel(
    const int* __restrict__ e1_idx, const int* __restrict__ r_idx,
    const float* __restrict__ E, const float* __restrict__ R,
    const float* __restrict__ lits, const float* __restrict__ c,
    const float* __restrict__ var_l, const float* __restrict__ nf,
    const float* __restrict__ bn0g, const float* __restrict__ bn0b,
    float* __restrict__ ws) {
  float* xT = ws + WS_XT;
  float* rT = ws + WS_RT;
  float* aT = ws + WS_AT;
  float* wT = ws + WS_WT;
  float* sl = ws + WS_SL;
  int tid = threadIdx.x;

  if (blockIdx.x == 0) {
    // bn0 over batch axis: thread = feature j
    if (tid < D1C) {
      int j = tid;
      float sum = 0.f, sq = 0.f;
      for (int b = 0; b < BB; b++) {
        float e = E[e1_idx[b] * D1C + j];
        sum += e; sq += e * e;
      }
      float mean = sum * (1.f / 64.f);
      float var  = sq  * (1.f / 64.f) - mean * mean;
      float inv  = __builtin_amdgcn_rsqf(var + BN_EPS);
      float g    = bn0g[j] * inv;
      float be   = bn0b[j] - mean * g;
      for (int b = 0; b < BB; b++) {
        xT[j * 64 + b] = g * E[e1_idx[b] * D1C + j] + be;
      }
    }
  } else if (blockIdx.x == 1) {
    // gather R rows (transposed)
    for (int idx = tid; idx < D2C * 64; idx += 256) {
      int k = idx >> 6, b = idx & 63;
      rT[idx] = R[r_idx[b] * D2C + k];
    }
  } else {
    // literal branch precompute: aT[l][b] = (n_h - c)*s ; wT[l][b] = nf[r]
    for (int idx = tid; idx < LLC * 64; idx += 256) {
      int l = idx >> 6, b = idx & 63;
      float s = sqrtf(LOG2E / var_l[l]);
      aT[idx] = (lits[e1_idx[b] * LLC + l] - c[l]) * s;
      wT[idx] = nf[r_idx[b] * LLC + l];
    }
    if (tid < LLC) sl[tid] = sqrtf(LOG2E / var_l[tid]);
  }
}

// ---------------------------------------------------------------------------
// Stage 1: y[k][j][b] = r[b,k] * sum_i x[b,i] * W[k,i,j]
// lane = b (64 exactly). W row values are wave-uniform -> s_load.
// grid (k=200, jq=10), block 128 (2 waves x 10-j tiles) -> 4000 waves.
// ---------------------------------------------------------------------------
__global__ __launch_bounds__(128) void stage1_kernel(
    const float* __restrict__ W, const float* __restrict__ ws_in,
    float* __restrict__ y) {
  const float* xT = ws_in + WS_XT;
  const float* rT = ws_in + WS_RT;
  int k = blockIdx.x, jq = blockIdx.y;
  int lane = threadIdx.x & 63;
  int wid = __builtin_amdgcn_readfirstlane(threadIdx.x >> 6);
  int j0 = jq * 20 + wid * 10;

  float r = rT[k * 64 + lane];
  float acc[10];
#pragma unroll
  for (int jj = 0; jj < 10; jj++) acc[jj] = 0.f;

  const float* Wk = W + (k * D1C) * D1C + j0;   // W[k][i][j0..]
  for (int i = 0; i < D1C; i++) {
    float xv = xT[i * 64 + lane];               // coalesced, L1-hot
    const float* wr = Wk + i * D1C;             // wave-uniform -> s_load
#pragma unroll
    for (int jj = 0; jj < 10; jj++) acc[jj] += xv * wr[jj];
  }

  float* yo = y + (k * D1C + j0) * 64 + lane;
#pragma unroll
  for (int jj = 0; jj < 10; jj++) yo[jj * 64] = r * acc[jj];
}

// ---------------------------------------------------------------------------
// Kernel C: x_out[b,j] = sum_k y[k][j][b], then bn1 over b -> x2T[j][b]
// block = j (200 blocks), 256 threads: lane=b, 4 k-quarters.
// ---------------------------------------------------------------------------
__global__ __launch_bounds__(256) void reduce_bn1_kernel(
    const float* __restrict__ y, const float* __restrict__ bn1g,
    const float* __restrict__ bn1b, float* __restrict__ ws) {
  float* x2T = ws + WS_X2T;
  int j = blockIdx.x;
  int tid = threadIdx.x, b = tid & 63, kq = tid >> 6;

  float s = 0.f;
  const float* yp = y + (kq * 50 * D1C + j) * 64 + b;
  for (int k = 0; k < 50; k++) s += yp[k * D1C * 64];

  __shared__ float part[256];
  part[tid] = s;
  __syncthreads();
  if (tid < 64) {
    float v = part[tid] + part[64 + tid] + part[128 + tid] + part[192 + tid];
    float sum = v, sq = v * v;
#pragma unroll
    for (int o = 32; o > 0; o >>= 1) {
      sum += __shfl_xor(sum, o, 64);
      sq  += __shfl_xor(sq,  o, 64);
    }
    float mean = sum * (1.f / 64.f);
    float var  = sq  * (1.f / 64.f) - mean * mean;
    float inv  = __builtin_amdgcn_rsqf(var + BN_EPS);
    float g    = bn1g[j] * inv;
    float be   = bn1b[j] - mean * g;
    x2T[j * 64 + tid] = g * v + be;
  }
}

// ---------------------------------------------------------------------------
// Final: out[b,n] = sigmoid( sum_j x2[b,j]E[n,j] + sum_l w[b,l]*exp2(-t^2) )
// 256 threads = 4 waves; lane = n (64 n per block); wave w covers b-chunk
// [w*16, w*16+16) with 16 accumulators. E staged transposed S[j][n] in 4
// quarters of 50 j (stride-65 rows: conflict-free stride-1 reads). The SAME
// LDS buffer is re-staged with scaled literals for the exp branch afterwards
// (union -> only 16.6 KB LDS -> occupancy no longer LDS-limited).
// x2 / a / w reads are wave-uniform -> s_load_x16.
// ---------------------------------------------------------------------------
__global__ __launch_bounds__(256, 4) void final_kernel(
    const float* __restrict__ E, const float* __restrict__ lits,
    const float* __restrict__ ws, float* __restrict__ out) {
  const float* aT  = ws + WS_AT;
  const float* wT  = ws + WS_WT;
  const float* sl  = ws + WS_SL;
  const float* x2T = ws + WS_X2T;

  __shared__ float S[64 * 65];   // union: EsT quarter [50][65] / Ls [64][65]

  int n0 = blockIdx.x * 64;
  int tid = threadIdx.x;
  int lane = tid & 63;
  int boff = __builtin_amdgcn_readfirstlane(tid >> 6) * 16;

  float acc[16];
#pragma unroll
  for (int bb = 0; bb < 16; bb++) acc[bb] = 0.f;

  // ---- score_l: 4 quarters of 50 j ----
  for (int q = 0; q < 4; q++) {
    __syncthreads();
    // stage E[n0..n0+63][q*50..q*50+49] transposed: S[j_local*65 + row]
    for (int idx = tid; idx < 64 * 25; idx += 256) {
      int row = idx / 25, c2 = idx % 25;
      const float2 v = *(const float2*)(E + (n0 + row) * D1C + q * 50 + c2 * 2);
      S[(c2 * 2 + 0) * 65 + row] = v.x;
      S[(c2 * 2 + 1) * 65 + row] = v.y;
    }
    __syncthreads();
    const float* x2p = x2T + q * 50 * 64 + boff;
    for (int j = 0; j < 50; j++) {
      float ev = S[j * 65 + lane];            // stride-1 across lanes
      const float* xw = x2p + j * 64;         // wave-uniform -> s_load_x16
#pragma unroll
      for (int bb = 0; bb < 16; bb++) acc[bb] += ev * xw[bb];
    }
  }

  // ---- restage literals into the same buffer: S[l*65 + row] = lits*scale ----
  __syncthreads();
  for (int idx = tid; idx < 64 * 16; idx += 256) {
    int row = idx >> 4, c4 = idx & 15;
    const float4 v = *(const float4*)(lits + (n0 + row) * LLC + c4 * 4);
    int l = c4 * 4;
    S[(l + 0) * 65 + row] = v.x * sl[l + 0];
    S[(l + 1) * 65 + row] = v.y * sl[l + 1];
    S[(l + 2) * 65 + row] = v.z * sl[l + 2];
    S[(l + 3) * 65 + row] = v.w * sl[l + 3];
  }
  __syncthreads();

  // ---- score_n: KBLN gaussian-kernel branch ----
  for (int l = 0; l < LLC; l++) {
    float lit = S[l * 65 + lane];
    const float* aw = aT + l * 64 + boff;     // wave-uniform -> s_load_x16
    const float* ww = wT + l * 64 + boff;
#pragma unroll
    for (int bb = 0; bb < 16; bb++) {
      float t = aw[bb] - lit;
      acc[bb] += ww[bb] * __builtin_amdgcn_exp2f(-t * t);
    }
  }

  // ---- sigmoid + coalesced store ----
#pragma unroll
  for (int bb = 0; bb < 16; bb++) {
    float s = acc[bb];
    float e = __builtin_amdgcn_exp2f(-LOG2E * s);
    out[(boff + bb) * NEC + n0 + lane] = __builtin_amdgcn_rcpf(1.f + e);
  }
}

// ---------------------------------------------------------------------------
extern "C" void kernel_launch(void* const* d_in, const int* in_sizes, int n_in,
                              void* d_out, int out_size, void* d_ws, size_t ws_size,
                              hipStream_t stream) {
  (void)in_sizes; (void)n_in; (void)out_size; (void)ws_size;
  const int*   e1    = (const int*)d_in[0];
  const int*   ri    = (const int*)d_in[1];
  const float* E     = (const float*)d_in[2];
  const float* R     = (const float*)d_in[3];
  const float* W     = (const float*)d_in[4];
  const float* lits  = (const float*)d_in[5];
  const float* c     = (const float*)d_in[6];
  const float* var_l = (const float*)d_in[7];
  const float* nf    = (const float*)d_in[8];
  const float* bn0g  = (const float*)d_in[9];
  const float* bn0b  = (const float*)d_in[10];
  const float* bn1g  = (const float*)d_in[11];
  const float* bn1b  = (const float*)d_in[12];
  float* out = (float*)d_out;
  float* ws  = (float*)d_ws;
  float* y   = ws + WS_Y;

  prep_kernel<<<3, 256, 0, stream>>>(e1, ri, E, R, lits, c, var_l, nf,
                                     bn0g, bn0b, ws);
  stage1_kernel<<<dim3(200, 10), 128, 0, stream>>>(W, ws, y);
  reduce_bn1_kernel<<<200, 256, 0, stream>>>(y, bn1g, bn1b, ws);
  final_kernel<<<625, 256, 0, stream>>>(E, lits, ws, out);
}